// Round 6
// baseline (67.852 us; speedup 1.0000x reference)
//
#include <hip/hip_runtime.h>
#include <math.h>

#define C_SIZE 2048
#define D_DIM  1024
#define H_DIM  1024
#define B_SIZE 32
#define S_LEN  64
#define G_NUM  32               // c-groups in fused pass
#define CG     (C_SIZE / G_NUM) // 64 c per block, 16 per wave

// ---------------- Kernel 1: hidden_proj[b][d] = sum_h hidden[b][h] * W[d][h]
// grid = (B_SIZE, 32): 1024 blocks, 32 d-rows per block, 8 per wave.
__global__ __launch_bounds__(256) void hp_kernel(const float* __restrict__ hidden,
                                                 const float* __restrict__ W,
                                                 float* __restrict__ hp) {
    int b    = blockIdx.x;             // 0..31
    int dg   = blockIdx.y;             // 0..31
    int lane = threadIdx.x & 63;
    int wave = threadIdx.x >> 6;       // 0..3

    const float* hrow = hidden + b * H_DIM;
    float4 h4[4];
#pragma unroll
    for (int k = 0; k < 4; ++k) h4[k] = *(const float4*)(hrow + k * 256 + 4 * lane);

    const int d0 = dg * 32 + wave * 8;                 // 8 rows per wave
    const float* wp = W + (size_t)d0 * H_DIM + 4 * lane;
    float4 wb[2][4];
#pragma unroll
    for (int k = 0; k < 4; ++k) wb[0][k] = *(const float4*)(wp + k * 256);

#pragma unroll
    for (int i = 0; i < 8; ++i) {
        if (i < 7) {
            const float* wn = wp + (size_t)(i + 1) * H_DIM;
#pragma unroll
            for (int k = 0; k < 4; ++k) wb[(i + 1) & 1][k] = *(const float4*)(wn + k * 256);
        }
        float s = 0.f;
#pragma unroll
        for (int k = 0; k < 4; ++k) {
            float4 w4 = wb[i & 1][k];
            s += w4.x * h4[k].x + w4.y * h4[k].y + w4.z * h4[k].z + w4.w * h4[k].w;
        }
        for (int off = 32; off > 0; off >>= 1) s += __shfl_xor(s, off);
        if (lane == 0) hp[b * D_DIM + d0 + i] = s;
    }
}

// ---------------- Kernel 2: fused scores + online-softmax partial ctx accumulation
// grid = (G_NUM, B_SIZE), block = 256 (4 waves). Wave w handles 16 consecutive c's.
// Distance-2 load pipeline: while waiting on row i, row i+1 is in flight and
// row i+2 is issued immediately after the buffer copy.
__global__ __launch_bounds__(256, 4) void fused_kernel(const float* __restrict__ cv,
                                                       const float* __restrict__ hp,
                                                       const unsigned char* __restrict__ mask,
                                                       float* __restrict__ scoresT,
                                                       float* __restrict__ pm,
                                                       float* __restrict__ pl,
                                                       float* __restrict__ pacc) {
    int g    = blockIdx.x;
    int b    = blockIdx.y;
    int lane = threadIdx.x & 63;
    int wave = threadIdx.x >> 6;

    const float* hpb = hp + b * D_DIM;
    float4 hp4[4];
#pragma unroll
    for (int k = 0; k < 4; ++k) hp4[k] = *(const float4*)(hpb + k * 256 + 4 * lane);

    float  m = -3.0e38f, l = 0.f;
    float4 acc[4];
#pragma unroll
    for (int k = 0; k < 4; ++k) acc[k] = make_float4(0.f, 0.f, 0.f, 0.f);

    const int    c0      = g * CG + wave * (CG / 4);   // 16 c's for this wave
    const size_t cstride = (size_t)B_SIZE * D_DIM;
    const float* p0      = cv + ((size_t)c0 * B_SIZE + b) * D_DIM + 4 * lane;

    float4 bufA[4], bufB[4];
#pragma unroll
    for (int k = 0; k < 4; ++k) bufA[k] = *(const float4*)(p0 + k * 256);
#pragma unroll
    for (int k = 0; k < 4; ++k) bufB[k] = *(const float4*)(p0 + cstride + k * 256);

#pragma unroll 2
    for (int i = 0; i < 16; ++i) {
        // consume row i from its buffer (waits only on that buffer's loads;
        // the other buffer's row stays outstanding)
        float4 cvv[4];
#pragma unroll
        for (int k = 0; k < 4; ++k) cvv[k] = (i & 1) ? bufB[k] : bufA[k];

        // issue row i+2 into the buffer we just freed
        if (i < 14) {
            const float* pn = p0 + (size_t)(i + 2) * cstride;
            if (i & 1) {
#pragma unroll
                for (int k = 0; k < 4; ++k) bufB[k] = *(const float4*)(pn + k * 256);
            } else {
#pragma unroll
                for (int k = 0; k < 4; ++k) bufA[k] = *(const float4*)(pn + k * 256);
            }
        }

        // dot(cv_row, hp_row)
        float s = 0.f;
#pragma unroll
        for (int k = 0; k < 4; ++k) {
            s += cvv[k].x * hp4[k].x + cvv[k].y * hp4[k].y +
                 cvv[k].z * hp4[k].z + cvv[k].w * hp4[k].w;
        }
        for (int off = 32; off > 0; off >>= 1) s += __shfl_xor(s, off);

        int c = c0 + i;
        if (mask[c * B_SIZE + b]) s = -3.0e38f;
        if (lane == 0) scoresT[b * C_SIZE + c] = s;

        // online softmax update — s is wave-uniform, so this branch is uniform.
        if (s <= m) {
            float p = __expf(s - m);
            l += p;
#pragma unroll
            for (int k = 0; k < 4; ++k) {
                acc[k].x += p * cvv[k].x;
                acc[k].y += p * cvv[k].y;
                acc[k].z += p * cvv[k].z;
                acc[k].w += p * cvv[k].w;
            }
        } else {
            float scale = __expf(m - s);   // first real row: exp(-huge)=0 zeroes junk
            l = l * scale + 1.f;
#pragma unroll
            for (int k = 0; k < 4; ++k) {
                acc[k].x = acc[k].x * scale + cvv[k].x;
                acc[k].y = acc[k].y * scale + cvv[k].y;
                acc[k].z = acc[k].z * scale + cvv[k].z;
                acc[k].w = acc[k].w * scale + cvv[k].w;
            }
            m = s;
        }
    }

    // ---- combine the 4 waves' partials within the block
    __shared__ float sm[4], sl[4];
    __shared__ float accs[4][D_DIM];   // 16 KiB
    if (lane == 0) { sm[wave] = m; sl[wave] = l; }
    __syncthreads();

    float mb = fmaxf(fmaxf(sm[0], sm[1]), fmaxf(sm[2], sm[3]));
    float myscale = __expf(m - mb);
#pragma unroll
    for (int k = 0; k < 4; ++k) {
        float4 v = acc[k];
        v.x *= myscale; v.y *= myscale; v.z *= myscale; v.w *= myscale;
        *(float4*)&accs[wave][k * 256 + 4 * lane] = v;
    }
    float lb = 0.f;
#pragma unroll
    for (int w = 0; w < 4; ++w) lb += sl[w] * __expf(sm[w] - mb);
    __syncthreads();

    int t = threadIdx.x;   // 0..255, owns d = 4t..4t+3
    float4 r = make_float4(0.f, 0.f, 0.f, 0.f);
#pragma unroll
    for (int w = 0; w < 4; ++w) {
        float4 v = *(const float4*)&accs[w][t * 4];
        r.x += v.x; r.y += v.y; r.z += v.z; r.w += v.w;
    }
    *(float4*)(pacc + ((size_t)g * B_SIZE + b) * D_DIM + t * 4) = r;
    if (t == 0) { pm[g * B_SIZE + b] = mb; pl[g * B_SIZE + b] = lb; }
}

// ---------------- Kernel 3: reduce group partials -> ctx[b][d] in ws (+ M/L)
// grid = (B_SIZE, 4), block = 64 (1 wave). Block handles 256 d's.
__global__ __launch_bounds__(64) void ctx_kernel(const float* __restrict__ pm,
                                                 const float* __restrict__ pl,
                                                 const float* __restrict__ pacc,
                                                 float* __restrict__ Mb,
                                                 float* __restrict__ Lb,
                                                 float* __restrict__ ctxws) {
    int b     = blockIdx.x;
    int dbase = blockIdx.y * 256;
    int lane  = threadIdx.x;   // 0..63

    float mg = (lane < G_NUM) ? pm[lane * B_SIZE + b] : -3.0e38f;
    float M = mg;
    for (int off = 32; off > 0; off >>= 1) M = fmaxf(M, __shfl_xor(M, off));
    float lg = (lane < G_NUM) ? pl[lane * B_SIZE + b] * __expf(mg - M) : 0.f;
    float L = lg;
    for (int off = 32; off > 0; off >>= 1) L += __shfl_xor(L, off);

    __shared__ float ssc[G_NUM];
    if (lane < G_NUM) ssc[lane] = __expf(mg - M);
    __syncthreads();

    float4 r = make_float4(0.f, 0.f, 0.f, 0.f);
#pragma unroll 8
    for (int gi = 0; gi < G_NUM; ++gi) {
        float sc = ssc[gi];
        float4 v = *(const float4*)(pacc + ((size_t)gi * B_SIZE + b) * D_DIM + dbase + 4 * lane);
        r.x += sc * v.x; r.y += sc * v.y; r.z += sc * v.z; r.w += sc * v.w;
    }
    float invL = 1.f / L;
    r.x *= invL; r.y *= invL; r.z *= invL; r.w *= invL;
    *(float4*)(ctxws + b * D_DIM + dbase + 4 * lane) = r;

    if (blockIdx.y == 0 && lane == 0) { Mb[b] = M; Lb[b] = L; }
}

// ---------------- Kernel 4: per (s,b): broadcast ctx row + attn row
// grid = S_LEN*B_SIZE = 2048, block = 256
__global__ __launch_bounds__(256) void out_kernel(const float* __restrict__ ctxws,
                                                  const float* __restrict__ scoresT,
                                                  const float* __restrict__ Mb,
                                                  const float* __restrict__ Lb,
                                                  float* __restrict__ out_ctx,
                                                  float* __restrict__ out_attn) {
    int blk = blockIdx.x;          // s*B + b
    int b   = blk & (B_SIZE - 1);
    int t   = threadIdx.x;

    // context row (broadcast)
    float4 cx = *(const float4*)(ctxws + b * D_DIM + t * 4);
    *(float4*)(out_ctx + (size_t)blk * D_DIM + t * 4) = cx;

    // attention row
    float M    = Mb[b];
    float invL = 1.f / Lb[b];
    const float* srow = scoresT + b * C_SIZE;
    float4* orow = (float4*)(out_attn + (size_t)blk * C_SIZE);
#pragma unroll
    for (int k = 0; k < 2; ++k) {
        int c4 = t + k * 256;
        float4 sv = *(const float4*)(srow + c4 * 4);
        float4 av;
        av.x = __expf(sv.x - M) * invL;
        av.y = __expf(sv.y - M) * invL;
        av.z = __expf(sv.z - M) * invL;
        av.w = __expf(sv.w - M) * invL;
        orow[c4] = av;
    }
}

extern "C" void kernel_launch(void* const* d_in, const int* in_sizes, int n_in,
                              void* d_out, int out_size, void* d_ws, size_t ws_size,
                              hipStream_t stream) {
    // inputs: 0=seqlen(int,unused; S_LEN=64 static), 1=hidden[1,B,H] f32,
    //         2=contextvects[C,B,D] f32, 3=W[D,H] f32, 4=padding_mask[C,B] bool
    const float*         hidden = (const float*)d_in[1];
    const float*         cv     = (const float*)d_in[2];
    const float*         W      = (const float*)d_in[3];
    const unsigned char* mask   = (const unsigned char*)d_in[4];

    float* ws = (float*)d_ws;
    float* hp      = ws;                 // 32768
    float* scoresT = ws + 32768;         // 65536
    float* pm      = ws + 98304;         // 1024
    float* pl      = ws + 99328;         // 1024
    float* Mb      = ws + 100352;        // 32
    float* Lb      = ws + 100384;        // 32
    float* ctxws   = ws + 100416;        // 32768 (16B-aligned)
    float* pacc    = ws + 133184;        // G*B*D = 1048576 (16B-aligned)

    float* out_ctx  = (float*)d_out;                                  // [S,B,D]
    float* out_attn = (float*)d_out + (size_t)S_LEN * B_SIZE * D_DIM; // [S,B,C]

    hp_kernel<<<dim3(B_SIZE, 32), 256, 0, stream>>>(hidden, W, hp);
    fused_kernel<<<dim3(G_NUM, B_SIZE), 256, 0, stream>>>(cv, hp, mask, scoresT, pm, pl, pacc);
    ctx_kernel<<<dim3(B_SIZE, 4), 64, 0, stream>>>(pm, pl, pacc, Mb, Lb, ctxws);
    out_kernel<<<dim3(S_LEN * B_SIZE), 256, 0, stream>>>(ctxws, scoresT, Mb, Lb, out_ctx, out_attn);
}

// Round 7
// 66.887 us; speedup vs baseline: 1.0144x; 1.0144x over previous
//
#include <hip/hip_runtime.h>
#include <math.h>

#define C_SIZE 2048
#define D_DIM  1024
#define H_DIM  1024
#define B_SIZE 32
#define S_LEN  64
#define G_NUM  32               // c-groups in fused pass
#define CG     (C_SIZE / G_NUM) // 64 c per block, 16 per wave

// ---------------- Kernel 1: hidden_proj[b][d] = sum_h hidden[b][h] * W[d][h]
// grid = (B_SIZE, 32): 1024 blocks, 32 d-rows per block, 8 per wave.
__global__ __launch_bounds__(256) void hp_kernel(const float* __restrict__ hidden,
                                                 const float* __restrict__ W,
                                                 float* __restrict__ hp) {
    int b    = blockIdx.x;             // 0..31
    int dg   = blockIdx.y;             // 0..31
    int lane = threadIdx.x & 63;
    int wave = threadIdx.x >> 6;       // 0..3

    const float* hrow = hidden + b * H_DIM;
    float4 h4[4];
#pragma unroll
    for (int k = 0; k < 4; ++k) h4[k] = *(const float4*)(hrow + k * 256 + 4 * lane);

    const int d0 = dg * 32 + wave * 8;                 // 8 rows per wave
    const float* wp = W + (size_t)d0 * H_DIM + 4 * lane;
    float4 wb[2][4];
#pragma unroll
    for (int k = 0; k < 4; ++k) wb[0][k] = *(const float4*)(wp + k * 256);

#pragma unroll
    for (int i = 0; i < 8; ++i) {
        if (i < 7) {
            const float* wn = wp + (size_t)(i + 1) * H_DIM;
#pragma unroll
            for (int k = 0; k < 4; ++k) wb[(i + 1) & 1][k] = *(const float4*)(wn + k * 256);
        }
        float s = 0.f;
#pragma unroll
        for (int k = 0; k < 4; ++k) {
            float4 w4 = wb[i & 1][k];
            s += w4.x * h4[k].x + w4.y * h4[k].y + w4.z * h4[k].z + w4.w * h4[k].w;
        }
        for (int off = 32; off > 0; off >>= 1) s += __shfl_xor(s, off);
        if (lane == 0) hp[b * D_DIM + d0 + i] = s;
    }
}

// ---------------- Kernel 2: fused scores + online-softmax partial ctx accumulation
// grid = (G_NUM, B_SIZE), block = 256 (4 waves). Wave w handles 16 consecutive c's.
// Hot loop VMEM path contains ONLY the 4 prefetch loads: mask bytes are
// preloaded (shfl-broadcast per iteration), scores kept in a lane-selected
// register and stored once after the loop. Fully unrolled so all pipeline
// buffer indices are static.
__global__ __launch_bounds__(256, 4) void fused_kernel(const float* __restrict__ cv,
                                                       const float* __restrict__ hp,
                                                       const unsigned char* __restrict__ mask,
                                                       float* __restrict__ scoresT,
                                                       float* __restrict__ pm,
                                                       float* __restrict__ pl,
                                                       float* __restrict__ pacc) {
    int g    = blockIdx.x;
    int b    = blockIdx.y;
    int lane = threadIdx.x & 63;
    int wave = threadIdx.x >> 6;

    const float* hpb = hp + b * D_DIM;
    float4 hp4[4];
#pragma unroll
    for (int k = 0; k < 4; ++k) hp4[k] = *(const float4*)(hpb + k * 256 + 4 * lane);

    const int    c0      = g * CG + wave * (CG / 4);   // 16 c's for this wave
    const size_t cstride = (size_t)B_SIZE * D_DIM;
    const float* p0      = cv + ((size_t)c0 * B_SIZE + b) * D_DIM + 4 * lane;

    // preload this wave's 16 mask bytes: lane i<16 holds mask[(c0+i)*B + b]
    int mreg = 0;
    if (lane < 16) mreg = mask[(size_t)(c0 + lane) * B_SIZE + b];

    float  m = -3.0e38f, l = 0.f;
    float  myscore = 0.f;              // lane i<16 accumulates score for c0+i
    float4 acc[4];
#pragma unroll
    for (int k = 0; k < 4; ++k) acc[k] = make_float4(0.f, 0.f, 0.f, 0.f);

    float4 buf[2][4];
#pragma unroll
    for (int k = 0; k < 4; ++k) buf[0][k] = *(const float4*)(p0 + k * 256);
#pragma unroll
    for (int k = 0; k < 4; ++k) buf[1][k] = *(const float4*)(p0 + cstride + k * 256);

#pragma unroll
    for (int i = 0; i < 16; ++i) {
        // consume row i (waits only on this buffer's 4 loads; other row in flight)
        float4 cvv[4];
#pragma unroll
        for (int k = 0; k < 4; ++k) cvv[k] = buf[i & 1][k];

        // refill the freed buffer with row i+2
        if (i < 14) {
            const float* pn = p0 + (size_t)(i + 2) * cstride;
#pragma unroll
            for (int k = 0; k < 4; ++k) buf[i & 1][k] = *(const float4*)(pn + k * 256);
        }

        // dot(cv_row, hp_row)
        float s = 0.f;
#pragma unroll
        for (int k = 0; k < 4; ++k) {
            s += cvv[k].x * hp4[k].x + cvv[k].y * hp4[k].y +
                 cvv[k].z * hp4[k].z + cvv[k].w * hp4[k].w;
        }
        for (int off = 32; off > 0; off >>= 1) s += __shfl_xor(s, off);

        // mask via register broadcast (no VMEM in loop)
        if (__shfl(mreg, i, 64)) s = -3.0e38f;
        if (lane == i) myscore = s;    // i is a literal (full unroll)

        // online softmax update — s is wave-uniform, so this branch is uniform.
        if (s <= m) {
            float p = __expf(s - m);
            l += p;
#pragma unroll
            for (int k = 0; k < 4; ++k) {
                acc[k].x += p * cvv[k].x;
                acc[k].y += p * cvv[k].y;
                acc[k].z += p * cvv[k].z;
                acc[k].w += p * cvv[k].w;
            }
        } else {
            float scale = __expf(m - s);   // first real row: exp(-huge)=0 zeroes junk
            l = l * scale + 1.f;
#pragma unroll
            for (int k = 0; k < 4; ++k) {
                acc[k].x = acc[k].x * scale + cvv[k].x;
                acc[k].y = acc[k].y * scale + cvv[k].y;
                acc[k].z = acc[k].z * scale + cvv[k].z;
                acc[k].w = acc[k].w * scale + cvv[k].w;
            }
            m = s;
        }
    }

    // write this wave's 16 scores in one shot
    if (lane < 16) scoresT[b * C_SIZE + c0 + lane] = myscore;

    // ---- combine the 4 waves' partials within the block
    __shared__ float sm[4], sl[4];
    __shared__ float accs[4][D_DIM];   // 16 KiB
    if (lane == 0) { sm[wave] = m; sl[wave] = l; }
    __syncthreads();

    float mb = fmaxf(fmaxf(sm[0], sm[1]), fmaxf(sm[2], sm[3]));
    float myscale = __expf(m - mb);
#pragma unroll
    for (int k = 0; k < 4; ++k) {
        float4 v = acc[k];
        v.x *= myscale; v.y *= myscale; v.z *= myscale; v.w *= myscale;
        *(float4*)&accs[wave][k * 256 + 4 * lane] = v;
    }
    float lb = 0.f;
#pragma unroll
    for (int w = 0; w < 4; ++w) lb += sl[w] * __expf(sm[w] - mb);
    __syncthreads();

    int t = threadIdx.x;   // 0..255, owns d = 4t..4t+3
    float4 r = make_float4(0.f, 0.f, 0.f, 0.f);
#pragma unroll
    for (int w = 0; w < 4; ++w) {
        float4 v = *(const float4*)&accs[w][t * 4];
        r.x += v.x; r.y += v.y; r.z += v.z; r.w += v.w;
    }
    *(float4*)(pacc + ((size_t)g * B_SIZE + b) * D_DIM + t * 4) = r;
    if (t == 0) { pm[g * B_SIZE + b] = mb; pl[g * B_SIZE + b] = lb; }
}

// ---------------- Kernel 3: reduce group partials -> ctx[b][d] in ws (+ M/L)
// grid = (B_SIZE, 4), block = 64 (1 wave). Block handles 256 d's.
__global__ __launch_bounds__(64) void ctx_kernel(const float* __restrict__ pm,
                                                 const float* __restrict__ pl,
                                                 const float* __restrict__ pacc,
                                                 float* __restrict__ Mb,
                                                 float* __restrict__ Lb,
                                                 float* __restrict__ ctxws) {
    int b     = blockIdx.x;
    int dbase = blockIdx.y * 256;
    int lane  = threadIdx.x;   // 0..63

    float mg = (lane < G_NUM) ? pm[lane * B_SIZE + b] : -3.0e38f;
    float M = mg;
    for (int off = 32; off > 0; off >>= 1) M = fmaxf(M, __shfl_xor(M, off));
    float lg = (lane < G_NUM) ? pl[lane * B_SIZE + b] * __expf(mg - M) : 0.f;
    float L = lg;
    for (int off = 32; off > 0; off >>= 1) L += __shfl_xor(L, off);

    __shared__ float ssc[G_NUM];
    if (lane < G_NUM) ssc[lane] = __expf(mg - M);
    __syncthreads();

    float4 r = make_float4(0.f, 0.f, 0.f, 0.f);
#pragma unroll 8
    for (int gi = 0; gi < G_NUM; ++gi) {
        float sc = ssc[gi];
        float4 v = *(const float4*)(pacc + ((size_t)gi * B_SIZE + b) * D_DIM + dbase + 4 * lane);
        r.x += sc * v.x; r.y += sc * v.y; r.z += sc * v.z; r.w += sc * v.w;
    }
    float invL = 1.f / L;
    r.x *= invL; r.y *= invL; r.z *= invL; r.w *= invL;
    *(float4*)(ctxws + b * D_DIM + dbase + 4 * lane) = r;

    if (blockIdx.y == 0 && lane == 0) { Mb[b] = M; Lb[b] = L; }
}

// ---------------- Kernel 4: per (s,b): broadcast ctx row + attn row
// grid = S_LEN*B_SIZE = 2048, block = 256
__global__ __launch_bounds__(256) void out_kernel(const float* __restrict__ ctxws,
                                                  const float* __restrict__ scoresT,
                                                  const float* __restrict__ Mb,
                                                  const float* __restrict__ Lb,
                                                  float* __restrict__ out_ctx,
                                                  float* __restrict__ out_attn) {
    int blk = blockIdx.x;          // s*B + b
    int b   = blk & (B_SIZE - 1);
    int t   = threadIdx.x;

    // context row (broadcast)
    float4 cx = *(const float4*)(ctxws + b * D_DIM + t * 4);
    *(float4*)(out_ctx + (size_t)blk * D_DIM + t * 4) = cx;

    // attention row
    float M    = Mb[b];
    float invL = 1.f / Lb[b];
    const float* srow = scoresT + b * C_SIZE;
    float4* orow = (float4*)(out_attn + (size_t)blk * C_SIZE);
#pragma unroll
    for (int k = 0; k < 2; ++k) {
        int c4 = t + k * 256;
        float4 sv = *(const float4*)(srow + c4 * 4);
        float4 av;
        av.x = __expf(sv.x - M) * invL;
        av.y = __expf(sv.y - M) * invL;
        av.z = __expf(sv.z - M) * invL;
        av.w = __expf(sv.w - M) * invL;
        orow[c4] = av;
    }
}

extern "C" void kernel_launch(void* const* d_in, const int* in_sizes, int n_in,
                              void* d_out, int out_size, void* d_ws, size_t ws_size,
                              hipStream_t stream) {
    // inputs: 0=seqlen(int,unused; S_LEN=64 static), 1=hidden[1,B,H] f32,
    //         2=contextvects[C,B,D] f32, 3=W[D,H] f32, 4=padding_mask[C,B] bool
    const float*         hidden = (const float*)d_in[1];
    const float*         cv     = (const float*)d_in[2];
    const float*         W      = (const float*)d_in[3];
    const unsigned char* mask   = (const unsigned char*)d_in[4];

    float* ws = (float*)d_ws;
    float* hp      = ws;                 // 32768
    float* scoresT = ws + 32768;         // 65536
    float* pm      = ws + 98304;         // 1024
    float* pl      = ws + 99328;         // 1024
    float* Mb      = ws + 100352;        // 32
    float* Lb      = ws + 100384;        // 32
    float* ctxws   = ws + 100416;        // 32768 (16B-aligned)
    float* pacc    = ws + 133184;        // G*B*D = 1048576 (16B-aligned)

    float* out_ctx  = (float*)d_out;                                  // [S,B,D]
    float* out_attn = (float*)d_out + (size_t)S_LEN * B_SIZE * D_DIM; // [S,B,C]

    hp_kernel<<<dim3(B_SIZE, 32), 256, 0, stream>>>(hidden, W, hp);
    fused_kernel<<<dim3(G_NUM, B_SIZE), 256, 0, stream>>>(cv, hp, mask, scoresT, pm, pl, pacc);
    ctx_kernel<<<dim3(B_SIZE, 4), 64, 0, stream>>>(pm, pl, pacc, Mb, Lb, ctxws);
    out_kernel<<<dim3(S_LEN * B_SIZE), 256, 0, stream>>>(ctxws, scoresT, Mb, Lb, out_ctx, out_attn);
}

// Round 8
// 64.560 us; speedup vs baseline: 1.0510x; 1.0361x over previous
//
#include <hip/hip_runtime.h>
#include <math.h>

#define C_SIZE 2048
#define D_DIM  1024
#define H_DIM  1024
#define B_SIZE 32
#define S_LEN  64
#define G_NUM  8                // c-groups in fused pass (256 c per block)

// ---------------- Kernel 1: hidden_proj[b][d] = sum_h hidden[b][h] * W[d][h]
// grid = (B_SIZE, 32): 1024 blocks, 32 d-rows per block, 8 per wave.
__global__ __launch_bounds__(256) void hp_kernel(const float* __restrict__ hidden,
                                                 const float* __restrict__ W,
                                                 float* __restrict__ hp) {
    int b    = blockIdx.x;             // 0..31
    int dg   = blockIdx.y;             // 0..31
    int lane = threadIdx.x & 63;
    int wave = threadIdx.x >> 6;       // 0..3

    const float* hrow = hidden + b * H_DIM;
    float4 h4[4];
#pragma unroll
    for (int k = 0; k < 4; ++k) h4[k] = *(const float4*)(hrow + k * 256 + 4 * lane);

    const int d0 = dg * 32 + wave * 8;                 // 8 rows per wave
    const float* wp = W + (size_t)d0 * H_DIM + 4 * lane;
    float4 wb[2][4];
#pragma unroll
    for (int k = 0; k < 4; ++k) wb[0][k] = *(const float4*)(wp + k * 256);

#pragma unroll
    for (int i = 0; i < 8; ++i) {
        if (i < 7) {
            const float* wn = wp + (size_t)(i + 1) * H_DIM;
#pragma unroll
            for (int k = 0; k < 4; ++k) wb[(i + 1) & 1][k] = *(const float4*)(wn + k * 256);
        }
        float s = 0.f;
#pragma unroll
        for (int k = 0; k < 4; ++k) {
            float4 w4 = wb[i & 1][k];
            s += w4.x * h4[k].x + w4.y * h4[k].y + w4.z * h4[k].z + w4.w * h4[k].w;
        }
        for (int off = 32; off > 0; off >>= 1) s += __shfl_xor(s, off);
        if (lane == 0) hp[b * D_DIM + d0 + i] = s;
    }
}

// ---------------- Kernel 2: fused scores + online-softmax partial ctx accumulation
// grid = (G_NUM=8, B_SIZE), block = 1024 (16 waves). Wave w handles 16 consecutive c's.
// Inner loop identical to the proven round-7 version (depth-2 pipeline, clean VMEM path).
__global__ __launch_bounds__(1024, 4) void fused_kernel(const float* __restrict__ cv,
                                                        const float* __restrict__ hp,
                                                        const unsigned char* __restrict__ mask,
                                                        float* __restrict__ scoresT,
                                                        float* __restrict__ pm,
                                                        float* __restrict__ pl,
                                                        float* __restrict__ pacc) {
    int g    = blockIdx.x;             // 0..7
    int b    = blockIdx.y;             // 0..31
    int tid  = threadIdx.x;            // 0..1023
    int lane = tid & 63;
    int wave = tid >> 6;               // 0..15

    const float* hpb = hp + b * D_DIM;
    float4 hp4[4];
#pragma unroll
    for (int k = 0; k < 4; ++k) hp4[k] = *(const float4*)(hpb + k * 256 + 4 * lane);

    const int    c0      = g * 256 + wave * 16;        // 16 c's for this wave
    const size_t cstride = (size_t)B_SIZE * D_DIM;
    const float* p0      = cv + ((size_t)c0 * B_SIZE + b) * D_DIM + 4 * lane;

    // preload this wave's 16 mask bytes: lane i<16 holds mask[(c0+i)*B + b]
    int mreg = 0;
    if (lane < 16) mreg = mask[(size_t)(c0 + lane) * B_SIZE + b];

    float  m = -3.0e38f, l = 0.f;
    float  myscore = 0.f;              // lane i<16 holds score for c0+i
    float4 acc[4];
#pragma unroll
    for (int k = 0; k < 4; ++k) acc[k] = make_float4(0.f, 0.f, 0.f, 0.f);

    float4 buf[2][4];
#pragma unroll
    for (int k = 0; k < 4; ++k) buf[0][k] = *(const float4*)(p0 + k * 256);
#pragma unroll
    for (int k = 0; k < 4; ++k) buf[1][k] = *(const float4*)(p0 + cstride + k * 256);

#pragma unroll
    for (int i = 0; i < 16; ++i) {
        float4 cvv[4];
#pragma unroll
        for (int k = 0; k < 4; ++k) cvv[k] = buf[i & 1][k];

        if (i < 14) {
            const float* pn = p0 + (size_t)(i + 2) * cstride;
#pragma unroll
            for (int k = 0; k < 4; ++k) buf[i & 1][k] = *(const float4*)(pn + k * 256);
        }

        float s = 0.f;
#pragma unroll
        for (int k = 0; k < 4; ++k) {
            s += cvv[k].x * hp4[k].x + cvv[k].y * hp4[k].y +
                 cvv[k].z * hp4[k].z + cvv[k].w * hp4[k].w;
        }
        for (int off = 32; off > 0; off >>= 1) s += __shfl_xor(s, off);

        if (__shfl(mreg, i, 64)) s = -3.0e38f;
        if (lane == i) myscore = s;

        // online softmax update — s is wave-uniform, so this branch is uniform.
        if (s <= m) {
            float p = __expf(s - m);
            l += p;
#pragma unroll
            for (int k = 0; k < 4; ++k) {
                acc[k].x += p * cvv[k].x;
                acc[k].y += p * cvv[k].y;
                acc[k].z += p * cvv[k].z;
                acc[k].w += p * cvv[k].w;
            }
        } else {
            float scale = __expf(m - s);   // first real row: exp(-huge)=0 zeroes junk
            l = l * scale + 1.f;
#pragma unroll
            for (int k = 0; k < 4; ++k) {
                acc[k].x = acc[k].x * scale + cvv[k].x;
                acc[k].y = acc[k].y * scale + cvv[k].y;
                acc[k].z = acc[k].z * scale + cvv[k].z;
                acc[k].w = acc[k].w * scale + cvv[k].w;
            }
            m = s;
        }
    }

    // write this wave's 16 scores in one shot
    if (lane < 16) scoresT[b * C_SIZE + c0 + lane] = myscore;

    // ---- combine the 16 waves' partials within the block
    __shared__ float sm[16], sl[16];
    __shared__ float accs[16][D_DIM];   // 64 KiB
    if (lane == 0) { sm[wave] = m; sl[wave] = l; }
    __syncthreads();

    float mb = sm[0];
#pragma unroll
    for (int w = 1; w < 16; ++w) mb = fmaxf(mb, sm[w]);

    float myscale = __expf(m - mb);
#pragma unroll
    for (int k = 0; k < 4; ++k) {
        float4 v = acc[k];
        v.x *= myscale; v.y *= myscale; v.z *= myscale; v.w *= myscale;
        *(float4*)&accs[wave][k * 256 + 4 * lane] = v;
    }
    float lb = 0.f;
#pragma unroll
    for (int w = 0; w < 16; ++w) lb += sl[w] * __expf(sm[w] - mb);
    __syncthreads();

    float r = 0.f;                     // thread tid owns d = tid
#pragma unroll
    for (int w = 0; w < 16; ++w) r += accs[w][tid];
    pacc[((size_t)g * B_SIZE + b) * D_DIM + tid] = r;
    if (tid == 0) { pm[g * B_SIZE + b] = mb; pl[g * B_SIZE + b] = lb; }
}

// ---------------- Kernel 3 (merged tail): per (s,b) block computes M/L from pm/pl,
// reduces ctx row from L2-resident pacc (1 MB), writes ctx row + attn row.
// grid = S_LEN*B_SIZE = 2048, block = 256
__global__ __launch_bounds__(256) void out_kernel(const float* __restrict__ pm,
                                                  const float* __restrict__ pl,
                                                  const float* __restrict__ pacc,
                                                  const float* __restrict__ scoresT,
                                                  float* __restrict__ out_ctx,
                                                  float* __restrict__ out_attn) {
    int blk  = blockIdx.x;         // s*B + b
    int b    = blk & (B_SIZE - 1);
    int t    = threadIdx.x;
    int lane = t & 63;
    int wave = t >> 6;

    __shared__ float ssc[G_NUM];
    __shared__ float sML[2];

    if (wave == 0) {
        float mg = (lane < G_NUM) ? pm[lane * B_SIZE + b] : -3.0e38f;
        float M = mg;
#pragma unroll
        for (int off = 4; off > 0; off >>= 1) M = fmaxf(M, __shfl_xor(M, off));
        float lg = (lane < G_NUM) ? pl[lane * B_SIZE + b] * __expf(mg - M) : 0.f;
        float L = lg;
#pragma unroll
        for (int off = 4; off > 0; off >>= 1) L += __shfl_xor(L, off);
        if (lane < G_NUM) ssc[lane] = __expf(mg - M);
        if (lane == 0) { sML[0] = M; sML[1] = L; }
    }
    __syncthreads();

    float M    = sML[0];
    float invL = 1.f / sML[1];

    // context row: thread t owns d = 4t..4t+3; pacc is L2-resident (1 MB)
    float4 r = make_float4(0.f, 0.f, 0.f, 0.f);
#pragma unroll
    for (int gi = 0; gi < G_NUM; ++gi) {
        float sc = ssc[gi];
        float4 v = *(const float4*)(pacc + ((size_t)gi * B_SIZE + b) * D_DIM + t * 4);
        r.x += sc * v.x; r.y += sc * v.y; r.z += sc * v.z; r.w += sc * v.w;
    }
    r.x *= invL; r.y *= invL; r.z *= invL; r.w *= invL;
    *(float4*)(out_ctx + (size_t)blk * D_DIM + t * 4) = r;

    // attention row
    const float* srow = scoresT + b * C_SIZE;
    float4* orow = (float4*)(out_attn + (size_t)blk * C_SIZE);
#pragma unroll
    for (int k = 0; k < 2; ++k) {
        int c4 = t + k * 256;
        float4 sv = *(const float4*)(srow + c4 * 4);
        float4 av;
        av.x = __expf(sv.x - M) * invL;
        av.y = __expf(sv.y - M) * invL;
        av.z = __expf(sv.z - M) * invL;
        av.w = __expf(sv.w - M) * invL;
        orow[c4] = av;
    }
}

extern "C" void kernel_launch(void* const* d_in, const int* in_sizes, int n_in,
                              void* d_out, int out_size, void* d_ws, size_t ws_size,
                              hipStream_t stream) {
    // inputs: 0=seqlen(int,unused; S_LEN=64 static), 1=hidden[1,B,H] f32,
    //         2=contextvects[C,B,D] f32, 3=W[D,H] f32, 4=padding_mask[C,B] bool
    const float*         hidden = (const float*)d_in[1];
    const float*         cv     = (const float*)d_in[2];
    const float*         W      = (const float*)d_in[3];
    const unsigned char* mask   = (const unsigned char*)d_in[4];

    float* ws = (float*)d_ws;
    float* hp      = ws;                 // 32768
    float* scoresT = ws + 32768;         // 65536  [b][c]
    float* pm      = ws + 98304;         // 256    [g][b]
    float* pl      = ws + 98560;         // 256
    float* pacc    = ws + 98816;         // 8*32*1024 = 262144 (16B-aligned)

    float* out_ctx  = (float*)d_out;                                  // [S,B,D]
    float* out_attn = (float*)d_out + (size_t)S_LEN * B_SIZE * D_DIM; // [S,B,C]

    hp_kernel<<<dim3(B_SIZE, 32), 256, 0, stream>>>(hidden, W, hp);
    fused_kernel<<<dim3(G_NUM, B_SIZE), 1024, 0, stream>>>(cv, hp, mask, scoresT, pm, pl, pacc);
    out_kernel<<<dim3(S_LEN * B_SIZE), 256, 0, stream>>>(pm, pl, pacc, scoresT, out_ctx, out_attn);
}